// Round 1
// baseline (695.616 us; speedup 1.0000x reference)
//
#include <hip/hip_runtime.h>

typedef short s16x8 __attribute__((ext_vector_type(8)));
typedef float f32x4 __attribute__((ext_vector_type(4)));
typedef float f32x4v __attribute__((ext_vector_type(4)));
typedef unsigned short u16x4 __attribute__((ext_vector_type(4)));

__device__ __forceinline__ unsigned short f2bf(float f) {
  unsigned int u = __float_as_uint(f);
  u += 0x7fffu + ((u >> 16) & 1u);
  return (unsigned short)(u >> 16);
}
__device__ __forceinline__ float bf2f(unsigned short h) {
  return __uint_as_float((unsigned int)h << 16);
}

__device__ __forceinline__ void gload16(const void* gp, void* lp) {
  __builtin_amdgcn_global_load_lds(
      (const __attribute__((address_space(1))) void*)gp,
      (__attribute__((address_space(3))) void*)lp,
      16, 0, 0);
}

// ---------------- cast f32 -> bf16, 4 at a time ----------------
__global__ void cast_f32_bf16_x4(const float* __restrict__ in,
                                 unsigned short* __restrict__ out, int n4) {
  int i = blockIdx.x * 256 + threadIdx.x;
  if (i >= n4) return;
  f32x4 v = *((const f32x4*)in + i);
  u16x4 o;
  o[0] = f2bf(v[0]); o[1] = f2bf(v[1]); o[2] = f2bf(v[2]); o[3] = f2bf(v[3]);
  *((u16x4*)out + i) = o;
}

// ---------------- G2[h][m][d] = sum_j g_kv[h][d][j] * Wlin[m][j], block-diag ----------------
__global__ void g2fill_kernel(const float* __restrict__ g_kv,
                              const float* __restrict__ Wlin,
                              unsigned short* __restrict__ G2) {
  int h = blockIdx.x, m = blockIdx.y, d = threadIdx.x;
  const float* gk = g_kv + ((size_t)h * 128 + d) * 128;
  const float* wl = Wlin + (size_t)m * 128;
  float s = 0.f;
  for (int j = 0; j < 128; ++j) s += gk[j] * wl[j];
  G2[((size_t)h * 128 + m) * 1536 + h * 128 + d] = f2bf(s);
}

// ---------------- GEMM: C[M,N] = A[M,K] @ B[N,K]^T (+ epilogue) ----------------
// MODE 0: bf16 out, +bias[cc]
// MODE 1: f32 out, +bias[cc]
// MODE 2: bf16 out, v*z[rr,cc>>7] + xloc[rr,cc] + bias[cc&127]
template <int MODE>
__global__ __launch_bounds__(256) void gemm_bt(
    const unsigned short* __restrict__ A, const unsigned short* __restrict__ B,
    const float* __restrict__ bias, void* __restrict__ Cout,
    int M, int N, int K,
    const float* __restrict__ xloc, const float* __restrict__ zbuf) {
  __shared__ __align__(16) unsigned short Asm_[128 * 64];
  __shared__ __align__(16) unsigned short Bsm_[128 * 64];
  const int tid = threadIdx.x;
  const int wid = tid >> 6, lane = tid & 63;
  const int mt = blockIdx.x, nt = blockIdx.y;
  const int wr = wid >> 1, wc = wid & 1;
  f32x4 acc[4][4] = {};

  // staging: chunk c covers 8 rows x 128B; lane -> row c*8+(lane>>3), colbyte (lane&7)*16
  // LDS holds element (row, c' ^ ((row&7)<<4)) at linear (row, c')
  const int st_srccol = ((((lane & 7) << 4) ^ ((lane >> 3) << 4)) >> 1);  // elements
  const int st_rowoff = (lane >> 3);

  for (int k0 = 0; k0 < K; k0 += 64) {
    __syncthreads();
#pragma unroll
    for (int r = 0; r < 4; ++r) {
      int c = wid * 4 + r;
      int lrow = c * 8 + st_rowoff;
      int arow = mt * 128 + lrow; if (arow > M - 1) arow = M - 1;
      gload16(A + (size_t)arow * K + k0 + st_srccol,
              (char*)Asm_ + c * 1024 + lane * 16);
      int brow = nt * 128 + lrow;
      gload16(B + (size_t)brow * K + k0 + st_srccol,
              (char*)Bsm_ + c * 1024 + lane * 16);
    }
    __syncthreads();
#pragma unroll
    for (int kk = 0; kk < 2; ++kk) {
      int cb = (kk * 64 + ((lane >> 4) << 4)) ^ ((lane & 7) << 4);
      s16x8 af[4], bfr[4];
#pragma unroll
      for (int m = 0; m < 4; ++m)
        af[m] = *(const s16x8*)((const char*)Asm_ + (wr * 64 + m * 16 + (lane & 15)) * 128 + cb);
#pragma unroll
      for (int n = 0; n < 4; ++n)
        bfr[n] = *(const s16x8*)((const char*)Bsm_ + (wc * 64 + n * 16 + (lane & 15)) * 128 + cb);
#pragma unroll
      for (int m = 0; m < 4; ++m)
#pragma unroll
        for (int n = 0; n < 4; ++n)
          acc[m][n] = __builtin_amdgcn_mfma_f32_16x16x32_bf16(af[m], bfr[n], acc[m][n], 0, 0, 0);
    }
  }
  const int rb = mt * 128 + wr * 64, cbse = nt * 128 + wc * 64;
#pragma unroll
  for (int m = 0; m < 4; ++m) {
#pragma unroll
    for (int n = 0; n < 4; ++n) {
#pragma unroll
      for (int rg = 0; rg < 4; ++rg) {
        int rr = rb + m * 16 + ((lane >> 4) << 2) + rg;
        int cc = cbse + n * 16 + (lane & 15);
        if (rr < M) {
          float v = acc[m][n][rg];
          if (MODE == 0) {
            v += bias[cc];
            ((unsigned short*)Cout)[(size_t)rr * N + cc] = f2bf(v);
          } else if (MODE == 1) {
            v += bias[cc];
            ((float*)Cout)[(size_t)rr * N + cc] = v;
          } else {
            v = v * zbuf[(size_t)rr * 12 + (cc >> 7)] + xloc[(size_t)rr * N + cc] + bias[cc & 127];
            ((unsigned short*)Cout)[(size_t)rr * N + cc] = f2bf(v);
          }
        }
      }
    }
  }
}

// ---------------- RMS + RoPE (+ z for the q path) ----------------
__global__ __launch_bounds__(256) void rms_rope_kernel(
    const unsigned short* __restrict__ pre, const float* __restrict__ freqs,
    const float* __restrict__ g, const float* __restrict__ g_kmean,
    unsigned short* __restrict__ outr, float* __restrict__ zout,
    int S, const int* __restrict__ hgp, const int* __restrict__ wgp) {
  const int s = blockIdx.x;
  const int tid = threadIdx.x;
  const int lane = tid & 63, wid = tid >> 6;
  const unsigned short* row = pre + (size_t)s * 1536;
  unsigned int pv0, pv1, pv2;
  float ssq = 0.f;
  {
    pv0 = *(const unsigned int*)(row + 2 * (tid));
    pv1 = *(const unsigned int*)(row + 2 * (tid + 256));
    pv2 = *(const unsigned int*)(row + 2 * (tid + 512));
    float a0 = bf2f((unsigned short)(pv0 & 0xffffu)), b0 = bf2f((unsigned short)(pv0 >> 16));
    float a1 = bf2f((unsigned short)(pv1 & 0xffffu)), b1 = bf2f((unsigned short)(pv1 >> 16));
    float a2 = bf2f((unsigned short)(pv2 & 0xffffu)), b2 = bf2f((unsigned short)(pv2 >> 16));
    ssq = a0 * a0 + b0 * b0 + a1 * a1 + b1 * b1 + a2 * a2 + b2 * b2;
  }
#pragma unroll
  for (int m = 1; m < 64; m <<= 1) ssq += __shfl_xor(ssq, m, 64);
  __shared__ float wpart[4];
  if (lane == 0) wpart[wid] = ssq;
  __syncthreads();
  float tot = wpart[0] + wpart[1] + wpart[2] + wpart[3];
  float rms = rsqrtf(tot * (1.0f / 1536.0f) + 1e-6f);
  const int Wg = *wgp;
  const int HWg = (*hgp) * Wg;
  int fi = s / HWg; int rem = s - fi * HWg;
  int hi = rem / Wg; int wi = rem - hi * Wg;
  unsigned int pvs[3] = {pv0, pv1, pv2};
#pragma unroll
  for (int rd = 0; rd < 3; ++rd) {
    int p = tid + rd * 256;
    int c = p & 63;
    int fidx = (c < 22) ? fi : ((c < 43) ? hi : wi);
    float cr = freqs[fidx * 128 + 2 * c];
    float ci = freqs[fidx * 128 + 2 * c + 1];
    float xr = bf2f((unsigned short)(pvs[rd] & 0xffffu)) * rms * g[2 * p];
    float xi = bf2f((unsigned short)(pvs[rd] >> 16)) * rms * g[2 * p + 1];
    float yr = xr * cr - xi * ci;
    float yi = xr * ci + xi * cr;
    unsigned int ow = (unsigned int)f2bf(yr) | ((unsigned int)f2bf(yi) << 16);
    *(unsigned int*)(outr + (size_t)s * 1536 + 2 * p) = ow;
    if (zout != nullptr) {
      int head = p >> 6;
      float part = fmaxf(xr, 0.f) * g_kmean[head * 128 + 2 * c] +
                   fmaxf(xi, 0.f) * g_kmean[head * 128 + 2 * c + 1];
#pragma unroll
      for (int m = 1; m < 64; m <<= 1) part += __shfl_xor(part, m, 64);
      if (lane == 0) zout[(size_t)s * 12 + head] = 1.0f / (part + 1e-6f);
    }
  }
}

// ---------------- V transpose: vpre (S,1536) bf16 -> vt (1536, S) bf16 ----------------
__global__ __launch_bounds__(256) void vtrans_kernel(const unsigned short* __restrict__ vpre,
                                                     unsigned short* __restrict__ vt, int S) {
  __shared__ unsigned short tile[64][66];
  int t0 = blockIdx.x * 64, c0 = blockIdx.y * 64;
  int tid = threadIdx.x;
#pragma unroll
  for (int rep = 0; rep < 16; ++rep) {
    int lin = rep * 256 + tid;
    int i = lin >> 6, j = lin & 63;
    int t = t0 + i; if (t > S - 1) t = S - 1;
    tile[i][j] = vpre[(size_t)t * 1536 + c0 + j];
  }
  __syncthreads();
#pragma unroll
  for (int rep = 0; rep < 16; ++rep) {
    int lin = rep * 256 + tid;
    int j = lin >> 6, i = lin & 63;
    int t = t0 + i;
    if (t < S) vt[(size_t)(c0 + j) * S + t] = tile[i][j];
  }
}

// ---------------- Flash attention ----------------
__global__ __launch_bounds__(256) void attn_kernel(
    const unsigned short* __restrict__ rq, const unsigned short* __restrict__ rk,
    const unsigned short* __restrict__ vt, float* __restrict__ xloc, int S) {
  __shared__ __align__(16) unsigned short Ks[64 * 128];
  __shared__ __align__(16) unsigned short Vs[128 * 64];
  __shared__ __align__(16) unsigned short Ps[4 * 16 * 64];
  const int tid = threadIdx.x, wid = tid >> 6, lane = tid & 63;
  const int h = blockIdx.y;
  const int q0 = blockIdx.x * 64 + wid * 16;

  s16x8 qf[4];
  {
    int qrow = q0 + (lane & 15); if (qrow > S - 1) qrow = S - 1;
    const unsigned short* qp = rq + (size_t)qrow * 1536 + h * 128 + ((lane >> 4) << 3);
#pragma unroll
    for (int kk = 0; kk < 4; ++kk) qf[kk] = *(const s16x8*)(qp + kk * 32);
  }
  f32x4 o[8] = {};
  float mrun[4], lrun[4];
#pragma unroll
  for (int r = 0; r < 4; ++r) { mrun[r] = -1e30f; lrun[r] = 0.f; }

  unsigned short* psw = Ps + wid * 1024;  // 16x64 bf16 per wave

  for (int t0 = 0; t0 < S; t0 += 64) {
    __syncthreads();
    // stage K tile [64 tok][128 d], XOR-swizzled via pre-swizzled global source
#pragma unroll
    for (int r = 0; r < 4; ++r) {
      int c = wid * 4 + r;
      int lrow = c * 4 + (lane >> 4);
      int cb = ((lane & 15) << 4) ^ ((lrow & 7) << 4);
      int trow = t0 + lrow; if (trow > S - 1) trow = S - 1;
      gload16(rk + (size_t)trow * 1536 + h * 128 + (cb >> 1),
              (char*)Ks + c * 1024 + lane * 16);
    }
    // stage V^T tile [128 d][64 tok]
#pragma unroll
    for (int r = 0; r < 4; ++r) {
      int c = wid * 4 + r;
      int lrow = c * 8 + (lane >> 3);
      int cb = ((lane & 7) << 4) ^ ((lane >> 3) << 4);
      int tok = t0 + (cb >> 1); if (tok + 8 > S) tok = S - 8;
      gload16(vt + (size_t)(h * 128 + lrow) * S + tok,
              (char*)Vs + c * 1024 + lane * 16);
    }
    __syncthreads();
    // QK^T
    f32x4 sc[4];
#pragma unroll
    for (int ct = 0; ct < 4; ++ct) {
      f32x4 a = {};
      int row = ct * 16 + (lane & 15);
#pragma unroll
      for (int kk = 0; kk < 4; ++kk) {
        int cb = (kk * 64 + ((lane >> 4) << 4)) ^ ((lane & 7) << 4);
        s16x8 kb = *(const s16x8*)((const char*)Ks + row * 256 + cb);
        a = __builtin_amdgcn_mfma_f32_16x16x32_bf16(qf[kk], kb, a, 0, 0, 0);
      }
      sc[ct] = a * 0.08838834764831845f;
    }
    // online softmax (rows: (lane>>4)*4+rg, cols: lane&15 within 16-group)
    float pscale[4];
    f32x4 pf[4];
    const int tb = t0 + (lane & 15);
    bool valid[4];
#pragma unroll
    for (int ct = 0; ct < 4; ++ct) valid[ct] = (tb + ct * 16) < S;
#pragma unroll
    for (int rg = 0; rg < 4; ++rg) {
      float mx = -1e30f;
#pragma unroll
      for (int ct = 0; ct < 4; ++ct) {
        float sv = valid[ct] ? sc[ct][rg] : -1e30f;
        mx = fmaxf(mx, sv);
      }
#pragma unroll
      for (int m = 1; m < 16; m <<= 1) mx = fmaxf(mx, __shfl_xor(mx, m, 64));
      float mnew = fmaxf(mrun[rg], mx);
      float scale = __expf(mrun[rg] - mnew);
      float rsum = 0.f;
#pragma unroll
      for (int ct = 0; ct < 4; ++ct) {
        float sv = valid[ct] ? sc[ct][rg] : -1e30f;
        float p = __expf(sv - mnew);
        pf[ct][rg] = p;
        rsum += p;
      }
#pragma unroll
      for (int m = 1; m < 16; m <<= 1) rsum += __shfl_xor(rsum, m, 64);
      lrun[rg] = lrun[rg] * scale + rsum;
      mrun[rg] = mnew;
      pscale[rg] = scale;
    }
    f32x4 pvs;
#pragma unroll
    for (int rg = 0; rg < 4; ++rg) pvs[rg] = pscale[rg];
#pragma unroll
    for (int nf = 0; nf < 8; ++nf) o[nf] *= pvs;
    // P -> wave-local LDS (swizzled)
#pragma unroll
    for (int ct = 0; ct < 4; ++ct) {
#pragma unroll
      for (int rg = 0; rg < 4; ++rg) {
        int prow = ((lane >> 4) << 2) + rg;
        int cb = ((ct * 16 + (lane & 15)) << 1) ^ ((prow & 7) << 4);
        *(unsigned short*)((char*)psw + prow * 128 + cb) = f2bf(pf[ct][rg]);
      }
    }
    // PV
#pragma unroll
    for (int tc = 0; tc < 2; ++tc) {
      int cb = (tc * 64 + ((lane >> 4) << 4)) ^ ((lane & 7) << 4);
      s16x8 pa = *(const s16x8*)((const char*)psw + (lane & 15) * 128 + cb);
#pragma unroll
      for (int nf = 0; nf < 8; ++nf) {
        s16x8 vb = *(const s16x8*)((const char*)Vs + (nf * 16 + (lane & 15)) * 128 + cb);
        o[nf] = __builtin_amdgcn_mfma_f32_16x16x32_bf16(pa, vb, o[nf], 0, 0, 0);
      }
    }
  }
  // epilogue
  f32x4 inv;
#pragma unroll
  for (int rg = 0; rg < 4; ++rg) inv[rg] = 1.0f / lrun[rg];
#pragma unroll
  for (int nf = 0; nf < 8; ++nf) {
#pragma unroll
    for (int rg = 0; rg < 4; ++rg) {
      int qrow = q0 + ((lane >> 4) << 2) + rg;
      if (qrow < S)
        xloc[(size_t)qrow * 1536 + h * 128 + nf * 16 + (lane & 15)] = o[nf][rg] * inv[rg];
    }
  }
}

extern "C" void kernel_launch(void* const* d_in, const int* in_sizes, int n_in,
                              void* d_out, int out_size, void* d_ws, size_t ws_size,
                              hipStream_t stream) {
  const float* x = (const float*)d_in[0];
  const float* freqs = (const float*)d_in[1];
  const float* g_kmean = (const float*)d_in[2];
  const float* g_kv = (const float*)d_in[3];
  const float* Wq = (const float*)d_in[4];  const float* bq = (const float*)d_in[5];
  const float* Wk = (const float*)d_in[6];  const float* bk = (const float*)d_in[7];
  const float* Wv = (const float*)d_in[8];  const float* bv = (const float*)d_in[9];
  const float* Wo = (const float*)d_in[10]; const float* bo = (const float*)d_in[11];
  const float* gq = (const float*)d_in[12]; const float* gk = (const float*)d_in[13];
  const float* Wlin = (const float*)d_in[14]; const float* blin = (const float*)d_in[15];
  const int* hgp = (const int*)d_in[17];
  const int* wgp = (const int*)d_in[18];

  const int S = in_sizes[0] / 1536;

  char* ws = (char*)d_ws;
  const size_t SZ = (size_t)S * 1536 * 2;       // bf16 (S,1536)
  const size_t WSZ = (size_t)1536 * 1536 * 2;   // bf16 1536^2
  size_t o_xbf = 0;
  size_t o_wq = o_xbf + SZ;
  size_t o_wk = o_wq + WSZ;
  size_t o_wv = o_wk + WSZ;
  size_t o_wo = o_wv + WSZ;
  size_t o_g2 = o_wo + WSZ;
  size_t o_qpre = o_g2 + WSZ;   // later reused as ybf
  size_t o_kpre = o_qpre + SZ;  // kpre+vpre later reused as xloc (f32, 2*SZ)
  size_t o_vpre = o_kpre + SZ;
  size_t o_rq = o_vpre + SZ;
  size_t o_rk = o_rq + SZ;
  size_t o_vt = o_rk + SZ;
  size_t o_z = o_vt + SZ;
  size_t need = o_z + (size_t)S * 12 * 4;
  if (ws_size < need) return;  // insufficient scratch: fail loudly (wrong output)

  unsigned short* xbf = (unsigned short*)(ws + o_xbf);
  unsigned short* wqb = (unsigned short*)(ws + o_wq);
  unsigned short* wkb = (unsigned short*)(ws + o_wk);
  unsigned short* wvb = (unsigned short*)(ws + o_wv);
  unsigned short* wob = (unsigned short*)(ws + o_wo);
  unsigned short* g2b = (unsigned short*)(ws + o_g2);
  unsigned short* qpre = (unsigned short*)(ws + o_qpre);
  unsigned short* kpre = (unsigned short*)(ws + o_kpre);
  unsigned short* vpre = (unsigned short*)(ws + o_vpre);
  unsigned short* rqb = (unsigned short*)(ws + o_rq);
  unsigned short* rkb = (unsigned short*)(ws + o_rk);
  unsigned short* vtb = (unsigned short*)(ws + o_vt);
  float* zbuf = (float*)(ws + o_z);
  float* xloc = (float*)(ws + o_kpre);           // aliases kpre+vpre (dead by then)
  unsigned short* ybf = (unsigned short*)(ws + o_qpre);  // aliases qpre (dead by then)

  // 1) casts
  {
    int n4 = (S * 1536) / 4;
    cast_f32_bf16_x4<<<(n4 + 255) / 256, 256, 0, stream>>>(x, xbf, n4);
    int w4 = (1536 * 1536) / 4;
    int wg = (w4 + 255) / 256;
    cast_f32_bf16_x4<<<wg, 256, 0, stream>>>(Wq, wqb, w4);
    cast_f32_bf16_x4<<<wg, 256, 0, stream>>>(Wk, wkb, w4);
    cast_f32_bf16_x4<<<wg, 256, 0, stream>>>(Wv, wvb, w4);
    cast_f32_bf16_x4<<<wg, 256, 0, stream>>>(Wo, wob, w4);
  }
  // 2) block-diagonal G2 = g_kv @ Wlin^T
  hipMemsetAsync(g2b, 0, WSZ, stream);
  g2fill_kernel<<<dim3(12, 128), 128, 0, stream>>>(g_kv, Wlin, g2b);

  // 3) projections
  dim3 ggrid((S + 127) / 128, 12);
  gemm_bt<0><<<ggrid, 256, 0, stream>>>(xbf, wqb, bq, qpre, S, 1536, 1536, nullptr, nullptr);
  gemm_bt<0><<<ggrid, 256, 0, stream>>>(xbf, wkb, bk, kpre, S, 1536, 1536, nullptr, nullptr);
  gemm_bt<0><<<ggrid, 256, 0, stream>>>(xbf, wvb, bv, vpre, S, 1536, 1536, nullptr, nullptr);

  // 4) RMS + RoPE (+z for q)
  rms_rope_kernel<<<S, 256, 0, stream>>>(qpre, freqs, gq, g_kmean, rqb, zbuf, S, hgp, wgp);
  rms_rope_kernel<<<S, 256, 0, stream>>>(kpre, freqs, gk, nullptr, rkb, nullptr, S, hgp, wgp);

  // 5) V transpose
  vtrans_kernel<<<dim3((S + 63) / 64, 24), 256, 0, stream>>>(vpre, vtb, S);

  // 6) attention -> xloc (f32)
  attn_kernel<<<dim3((S + 63) / 64, 12), 256, 0, stream>>>(rqb, rkb, vtb, xloc, S);

  // 7) xg = (rq @ G2) * z + xloc + blin  -> ybf
  gemm_bt<2><<<ggrid, 256, 0, stream>>>(rqb, g2b, blin, ybf, S, 1536, 1536, xloc, zbuf);

  // 8) out = ybf @ Wo^T + bo -> f32 d_out
  gemm_bt<1><<<ggrid, 256, 0, stream>>>(ybf, wob, bo, (float*)d_out, S, 1536, 1536, nullptr, nullptr);
}

// Round 2
// 693.128 us; speedup vs baseline: 1.0036x; 1.0036x over previous
//
#include <hip/hip_runtime.h>

typedef short s16x8 __attribute__((ext_vector_type(8)));
typedef float f32x4 __attribute__((ext_vector_type(4)));
typedef unsigned short u16x4 __attribute__((ext_vector_type(4)));

__device__ __forceinline__ unsigned short f2bf(float f) {
  unsigned int u = __float_as_uint(f);
  u += 0x7fffu + ((u >> 16) & 1u);
  return (unsigned short)(u >> 16);
}
__device__ __forceinline__ float bf2f(unsigned short h) {
  return __uint_as_float((unsigned int)h << 16);
}

__device__ __forceinline__ void gload16(const void* gp, void* lp) {
  __builtin_amdgcn_global_load_lds(
      (const __attribute__((address_space(1))) void*)gp,
      (__attribute__((address_space(3))) void*)lp,
      16, 0, 0);
}

// ---------------- cast f32 -> bf16, 4 at a time ----------------
__global__ void cast_f32_bf16_x4(const float* __restrict__ in,
                                 unsigned short* __restrict__ out, int n4) {
  int i = blockIdx.x * 256 + threadIdx.x;
  if (i >= n4) return;
  f32x4 v = *((const f32x4*)in + i);
  u16x4 o;
  o[0] = f2bf(v[0]); o[1] = f2bf(v[1]); o[2] = f2bf(v[2]); o[3] = f2bf(v[3]);
  *((u16x4*)out + i) = o;
}

// ---------------- G2[h][m][d] = sum_j g_kv[h][d][j] * Wlin[m][j], block-diag ----------------
__global__ void g2fill_kernel(const float* __restrict__ g_kv,
                              const float* __restrict__ Wlin,
                              unsigned short* __restrict__ G2) {
  int h = blockIdx.x, m = blockIdx.y, d = threadIdx.x;
  const float* gk = g_kv + ((size_t)h * 128 + d) * 128;
  const float* wl = Wlin + (size_t)m * 128;
  float s = 0.f;
  for (int j = 0; j < 128; ++j) s += gk[j] * wl[j];
  G2[((size_t)h * 128 + m) * 1536 + h * 128 + d] = f2bf(s);
}

// ---------------- GEMM: C[M,N] = A[M,K] @ B[N,K]^T (+ epilogue) ----------------
// MODE 0: bf16 out, +bias[cc]
// MODE 1: f32 out, +bias[cc]
// MODE 2: bf16 out, v*z[rr,cc>>7] + xloc[rr,cc] + bias[cc&127]
template <int MODE>
__global__ __launch_bounds__(256) void gemm_bt(
    const unsigned short* __restrict__ A, const unsigned short* __restrict__ B,
    const float* __restrict__ bias, void* __restrict__ Cout,
    int M, int N, int K,
    const float* __restrict__ xloc, const float* __restrict__ zbuf) {
  __shared__ __align__(16) unsigned short Asm_[128 * 64];
  __shared__ __align__(16) unsigned short Bsm_[128 * 64];
  const int tid = threadIdx.x;
  const int wid = tid >> 6, lane = tid & 63;
  const int mt = blockIdx.x, nt = blockIdx.y;
  const int wr = wid >> 1, wc = wid & 1;
  f32x4 acc[4][4] = {};

  const int st_srccol = ((((lane & 7) << 4) ^ ((lane >> 3) << 4)) >> 1);  // elements
  const int st_rowoff = (lane >> 3);

  for (int k0 = 0; k0 < K; k0 += 64) {
    __syncthreads();
#pragma unroll
    for (int r = 0; r < 4; ++r) {
      int c = wid * 4 + r;
      int lrow = c * 8 + st_rowoff;
      int arow = mt * 128 + lrow; if (arow > M - 1) arow = M - 1;
      gload16(A + (size_t)arow * K + k0 + st_srccol,
              (char*)Asm_ + c * 1024 + lane * 16);
      int brow = nt * 128 + lrow;
      gload16(B + (size_t)brow * K + k0 + st_srccol,
              (char*)Bsm_ + c * 1024 + lane * 16);
    }
    __syncthreads();
#pragma unroll
    for (int kk = 0; kk < 2; ++kk) {
      int cb = (kk * 64 + ((lane >> 4) << 4)) ^ ((lane & 7) << 4);
      s16x8 af[4], bfr[4];
#pragma unroll
      for (int m = 0; m < 4; ++m)
        af[m] = *(const s16x8*)((const char*)Asm_ + (wr * 64 + m * 16 + (lane & 15)) * 128 + cb);
#pragma unroll
      for (int n = 0; n < 4; ++n)
        bfr[n] = *(const s16x8*)((const char*)Bsm_ + (wc * 64 + n * 16 + (lane & 15)) * 128 + cb);
#pragma unroll
      for (int m = 0; m < 4; ++m)
#pragma unroll
        for (int n = 0; n < 4; ++n)
          acc[m][n] = __builtin_amdgcn_mfma_f32_16x16x32_bf16(af[m], bfr[n], acc[m][n], 0, 0, 0);
    }
  }
  const int rb = mt * 128 + wr * 64, cbse = nt * 128 + wc * 64;
#pragma unroll
  for (int m = 0; m < 4; ++m) {
#pragma unroll
    for (int n = 0; n < 4; ++n) {
#pragma unroll
      for (int rg = 0; rg < 4; ++rg) {
        int rr = rb + m * 16 + ((lane >> 4) << 2) + rg;
        int cc = cbse + n * 16 + (lane & 15);
        if (rr < M) {
          float v = acc[m][n][rg];
          if (MODE == 0) {
            v += bias[cc];
            ((unsigned short*)Cout)[(size_t)rr * N + cc] = f2bf(v);
          } else if (MODE == 1) {
            v += bias[cc];
            ((float*)Cout)[(size_t)rr * N + cc] = v;
          } else {
            v = v * zbuf[(size_t)rr * 12 + (cc >> 7)] + xloc[(size_t)rr * N + cc] + bias[cc & 127];
            ((unsigned short*)Cout)[(size_t)rr * N + cc] = f2bf(v);
          }
        }
      }
    }
  }
}

// ---------------- RMS + RoPE (+ z for the q path); input row stride ld ----------------
__global__ __launch_bounds__(256) void rms_rope_kernel(
    const unsigned short* __restrict__ pre, const float* __restrict__ freqs,
    const float* __restrict__ g, const float* __restrict__ g_kmean,
    unsigned short* __restrict__ outr, float* __restrict__ zout,
    int S, int ld, const int* __restrict__ hgp, const int* __restrict__ wgp) {
  const int s = blockIdx.x;
  const int tid = threadIdx.x;
  const int lane = tid & 63, wid = tid >> 6;
  const unsigned short* row = pre + (size_t)s * ld;
  unsigned int pv0, pv1, pv2;
  float ssq = 0.f;
  {
    pv0 = *(const unsigned int*)(row + 2 * (tid));
    pv1 = *(const unsigned int*)(row + 2 * (tid + 256));
    pv2 = *(const unsigned int*)(row + 2 * (tid + 512));
    float a0 = bf2f((unsigned short)(pv0 & 0xffffu)), b0 = bf2f((unsigned short)(pv0 >> 16));
    float a1 = bf2f((unsigned short)(pv1 & 0xffffu)), b1 = bf2f((unsigned short)(pv1 >> 16));
    float a2 = bf2f((unsigned short)(pv2 & 0xffffu)), b2 = bf2f((unsigned short)(pv2 >> 16));
    ssq = a0 * a0 + b0 * b0 + a1 * a1 + b1 * b1 + a2 * a2 + b2 * b2;
  }
#pragma unroll
  for (int m = 1; m < 64; m <<= 1) ssq += __shfl_xor(ssq, m, 64);
  __shared__ float wpart[4];
  if (lane == 0) wpart[wid] = ssq;
  __syncthreads();
  float tot = wpart[0] + wpart[1] + wpart[2] + wpart[3];
  float rms = rsqrtf(tot * (1.0f / 1536.0f) + 1e-6f);
  const int Wg = *wgp;
  const int HWg = (*hgp) * Wg;
  int fi = s / HWg; int rem = s - fi * HWg;
  int hi = rem / Wg; int wi = rem - hi * Wg;
  unsigned int pvs[3] = {pv0, pv1, pv2};
#pragma unroll
  for (int rd = 0; rd < 3; ++rd) {
    int p = tid + rd * 256;
    int c = p & 63;
    int fidx = (c < 22) ? fi : ((c < 43) ? hi : wi);
    float cr = freqs[fidx * 128 + 2 * c];
    float ci = freqs[fidx * 128 + 2 * c + 1];
    float xr = bf2f((unsigned short)(pvs[rd] & 0xffffu)) * rms * g[2 * p];
    float xi = bf2f((unsigned short)(pvs[rd] >> 16)) * rms * g[2 * p + 1];
    float yr = xr * cr - xi * ci;
    float yi = xr * ci + xi * cr;
    unsigned int ow = (unsigned int)f2bf(yr) | ((unsigned int)f2bf(yi) << 16);
    *(unsigned int*)(outr + (size_t)s * 1536 + 2 * p) = ow;
    if (zout != nullptr) {
      int head = p >> 6;
      float part = fmaxf(xr, 0.f) * g_kmean[head * 128 + 2 * c] +
                   fmaxf(xi, 0.f) * g_kmean[head * 128 + 2 * c + 1];
#pragma unroll
      for (int m = 1; m < 64; m <<= 1) part += __shfl_xor(part, m, 64);
      if (lane == 0) zout[(size_t)s * 12 + head] = 1.0f / (part + 1e-6f);
    }
  }
}

// ---------------- V transpose: vpre (S, ld cols used 64) bf16 -> vt (1536, S) bf16 ----------------
__global__ __launch_bounds__(256) void vtrans_kernel(const unsigned short* __restrict__ vpre,
                                                     unsigned short* __restrict__ vt, int S, int ld) {
  __shared__ unsigned short tile[64][66];
  int t0 = blockIdx.x * 64, c0 = blockIdx.y * 64;
  int tid = threadIdx.x;
#pragma unroll
  for (int rep = 0; rep < 16; ++rep) {
    int lin = rep * 256 + tid;
    int i = lin >> 6, j = lin & 63;
    int t = t0 + i; if (t > S - 1) t = S - 1;
    tile[i][j] = vpre[(size_t)t * ld + c0 + j];
  }
  __syncthreads();
#pragma unroll
  for (int rep = 0; rep < 16; ++rep) {
    int lin = rep * 256 + tid;
    int j = lin >> 6, i = lin & 63;
    int t = t0 + i;
    if (t < S) vt[(size_t)(c0 + j) * S + t] = tile[i][j];
  }
}

// ---------------- Flash attention, swapped-QK, 32 q-rows/wave, dbuf staging ----------------
__global__ __launch_bounds__(256) void attn_kernel(
    const unsigned short* __restrict__ rq, const unsigned short* __restrict__ rk,
    const unsigned short* __restrict__ vt, float* __restrict__ xloc, int S) {
  __shared__ __align__(16) unsigned short Ks[2][64 * 128];  // [tok][d] swizzled
  __shared__ __align__(16) unsigned short Vs[2][64 * 128];  // [d][tok] swizzled (from vt)
  __shared__ __align__(16) unsigned short Ps[4][32 * 64];   // per-wave [q][tok] swizzled
  const int tid = threadIdx.x, wid = tid >> 6, lane = tid & 63;
  const int g = lane >> 4, c = lane & 15;
  const int h = blockIdx.y;
  const int q0 = blockIdx.x * 128 + wid * 32;

  // Q B-fragments: qf[qh][kk] = Q[q = q0+qh*16+c][dim = kk*32 + g*8 + j]
  s16x8 qf[2][4];
#pragma unroll
  for (int qh = 0; qh < 2; ++qh) {
    int qrow = q0 + qh * 16 + c; if (qrow > S - 1) qrow = S - 1;
    const unsigned short* qp = rq + (size_t)qrow * 1536 + h * 128 + g * 8;
#pragma unroll
    for (int kk = 0; kk < 4; ++kk) qf[qh][kk] = *(const s16x8*)(qp + kk * 32);
  }
  f32x4 o[2][8] = {};
  float mrun[2] = {-3e38f, -3e38f};
  float lrun[2] = {0.f, 0.f};
  unsigned short* psw = Ps[wid];

  for (int pre = 0; pre < 1; ++pre) {  // prologue stage tile 0
#pragma unroll
    for (int r = 0; r < 4; ++r) {
      int ch = wid * 4 + r;
      int lrow = ch * 4 + (lane >> 4);
      int cb = ((lane & 15) << 4) ^ ((lrow & 7) << 4);
      int trow = lrow; if (trow > S - 1) trow = S - 1;
      gload16(rk + (size_t)trow * 1536 + h * 128 + (cb >> 1),
              (char*)Ks[0] + ch * 1024 + lane * 16);
      int drow = ch * 8 + (lane >> 3);
      int cb2 = ((lane & 7) << 4) ^ ((drow & 7) << 4);
      int tok = (cb2 >> 1); if (tok + 8 > S) tok = S - 8;
      gload16(vt + (size_t)(h * 128 + drow) * S + tok,
              (char*)Vs[0] + ch * 1024 + lane * 16);
    }
  }
  __syncthreads();
  int cur = 0;
  for (int t0 = 0; t0 < S; t0 += 64) {
    // issue next tile's staging first (hides under compute; barrier at loop end drains)
    if (t0 + 64 < S) {
      int nt0 = t0 + 64;
#pragma unroll
      for (int r = 0; r < 4; ++r) {
        int ch = wid * 4 + r;
        int lrow = ch * 4 + (lane >> 4);
        int cb = ((lane & 15) << 4) ^ ((lrow & 7) << 4);
        int trow = nt0 + lrow; if (trow > S - 1) trow = S - 1;
        gload16(rk + (size_t)trow * 1536 + h * 128 + (cb >> 1),
                (char*)Ks[cur ^ 1] + ch * 1024 + lane * 16);
        int drow = ch * 8 + (lane >> 3);
        int cb2 = ((lane & 7) << 4) ^ ((drow & 7) << 4);
        int tok = nt0 + (cb2 >> 1); if (tok + 8 > S) tok = S - 8;
        gload16(vt + (size_t)(h * 128 + drow) * S + tok,
                (char*)Vs[cur ^ 1] + ch * 1024 + lane * 16);
      }
    }
    // ---- QK^T (swapped): sc[qh][ct][rg] = S[token=ct*16+4g+rg][q=qh*16+c]
    f32x4 sc[2][4] = {};
#pragma unroll
    for (int ct = 0; ct < 4; ++ct) {
#pragma unroll
      for (int kk = 0; kk < 4; ++kk) {
        s16x8 kfr = *(const s16x8*)((const char*)Ks[cur] + (ct * 16 + c) * 256 +
                                    ((kk * 64 + (g << 4)) ^ ((c & 7) << 4)));
        sc[0][ct] = __builtin_amdgcn_mfma_f32_16x16x32_bf16(kfr, qf[0][kk], sc[0][ct], 0, 0, 0);
        sc[1][ct] = __builtin_amdgcn_mfma_f32_16x16x32_bf16(kfr, qf[1][kk], sc[1][ct], 0, 0, 0);
      }
    }
    const bool full = (t0 + 64 <= S);
#pragma unroll
    for (int qh = 0; qh < 2; ++qh) {
      float mx = -3e38f;
#pragma unroll
      for (int ct = 0; ct < 4; ++ct)
#pragma unroll
        for (int rg = 0; rg < 4; ++rg) {
          float sv = sc[qh][ct][rg] * 0.08838834764831845f;
          sc[qh][ct][rg] = sv;
          bool ok = full || (t0 + ct * 16 + 4 * g + rg < S);
          mx = fmaxf(mx, ok ? sv : -3e38f);
        }
      mx = fmaxf(mx, __shfl_xor(mx, 16, 64));
      mx = fmaxf(mx, __shfl_xor(mx, 32, 64));
      if (__any(mx > mrun[qh] + 8.0f)) {  // defer-max (T13)
        float mnew = fmaxf(mrun[qh], mx);
        float sf = __expf(mrun[qh] - mnew);
        mrun[qh] = mnew;
        lrun[qh] *= sf;
        f32x4 sv4;
#pragma unroll
        for (int rg = 0; rg < 4; ++rg) sv4[rg] = __shfl(sf, (g << 2) + rg, 64);
#pragma unroll
        for (int nf = 0; nf < 8; ++nf) o[qh][nf] *= sv4;
      }
      float m = mrun[qh], rsum = 0.f;
      unsigned int pk[8];
#pragma unroll
      for (int ct = 0; ct < 4; ++ct) {
#pragma unroll
        for (int hh = 0; hh < 2; ++hh) {
          float p0, p1;
          if (full) {
            p0 = __expf(sc[qh][ct][2 * hh] - m);
            p1 = __expf(sc[qh][ct][2 * hh + 1] - m);
          } else {
            int T = t0 + ct * 16 + 4 * g + 2 * hh;
            p0 = (T < S) ? __expf(sc[qh][ct][2 * hh] - m) : 0.f;
            p1 = (T + 1 < S) ? __expf(sc[qh][ct][2 * hh + 1] - m) : 0.f;
          }
          // truncate to bf16; accumulate the truncated values so P and l are consistent
          unsigned int u0 = __float_as_uint(p0) & 0xffff0000u;
          unsigned int u1 = __float_as_uint(p1) & 0xffff0000u;
          rsum += __uint_as_float(u0) + __uint_as_float(u1);
          pk[ct * 2 + hh] = (u0 >> 16) | u1;
        }
      }
      rsum += __shfl_xor(rsum, 16, 64);
      rsum += __shfl_xor(rsum, 32, 64);
      lrun[qh] += rsum;
      char* prow = (char*)psw + (qh * 16 + c) * 128;
#pragma unroll
      for (int ct = 0; ct < 4; ++ct) {
        uint2 w; w.x = pk[ct * 2]; w.y = pk[ct * 2 + 1];
        *(uint2*)(prow + ((ct * 32 + g * 8) ^ ((c & 7) << 4))) = w;
      }
    }
    // ---- PV: o[qh] += P[q][tok] @ Vt[d][tok]
#pragma unroll
    for (int kt = 0; kt < 2; ++kt) {
      const int pb = (kt * 64 + (g << 4)) ^ ((c & 7) << 4);
      s16x8 pa0 = *(const s16x8*)((const char*)psw + c * 128 + pb);
      s16x8 pa1 = *(const s16x8*)((const char*)psw + (16 + c) * 128 + pb);
#pragma unroll
      for (int nf = 0; nf < 8; ++nf) {
        s16x8 vfr = *(const s16x8*)((const char*)Vs[cur] + (nf * 16 + c) * 128 + pb);
        o[0][nf] = __builtin_amdgcn_mfma_f32_16x16x32_bf16(pa0, vfr, o[0][nf], 0, 0, 0);
        o[1][nf] = __builtin_amdgcn_mfma_f32_16x16x32_bf16(pa1, vfr, o[1][nf], 0, 0, 0);
      }
    }
    __syncthreads();
    cur ^= 1;
  }
  // epilogue: rows q = q0+qh*16+4g+rg, cols d = nf*16+c
#pragma unroll
  for (int qh = 0; qh < 2; ++qh) {
    float invl = 1.0f / lrun[qh];
    f32x4 iv;
#pragma unroll
    for (int rg = 0; rg < 4; ++rg) iv[rg] = __shfl(invl, (g << 2) + rg, 64);
#pragma unroll
    for (int nf = 0; nf < 8; ++nf) {
#pragma unroll
      for (int rg = 0; rg < 4; ++rg) {
        int qrow = q0 + qh * 16 + 4 * g + rg;
        if (qrow < S)
          xloc[(size_t)qrow * 1536 + h * 128 + nf * 16 + c] = o[qh][nf][rg] * iv[rg];
      }
    }
  }
}

extern "C" void kernel_launch(void* const* d_in, const int* in_sizes, int n_in,
                              void* d_out, int out_size, void* d_ws, size_t ws_size,
                              hipStream_t stream) {
  const float* x = (const float*)d_in[0];
  const float* freqs = (const float*)d_in[1];
  const float* g_kmean = (const float*)d_in[2];
  const float* g_kv = (const float*)d_in[3];
  const float* Wq = (const float*)d_in[4];  const float* bq = (const float*)d_in[5];
  const float* Wk = (const float*)d_in[6];  const float* bk = (const float*)d_in[7];
  const float* Wv = (const float*)d_in[8];  const float* bv = (const float*)d_in[9];
  const float* Wo = (const float*)d_in[10]; const float* bo = (const float*)d_in[11];
  const float* gq = (const float*)d_in[12]; const float* gk = (const float*)d_in[13];
  const float* Wlin = (const float*)d_in[14]; const float* blin = (const float*)d_in[15];
  const int* hgp = (const int*)d_in[17];
  const int* wgp = (const int*)d_in[18];

  const int S = in_sizes[0] / 1536;

  char* ws = (char*)d_ws;
  const size_t SZ = (size_t)S * 1536 * 2;        // bf16 (S,1536)
  const size_t WSZ = (size_t)1536 * 1536 * 2;    // bf16 1536^2
  const size_t QKVSZ = (size_t)S * 4608 * 2;     // bf16 (S,4608)
  size_t o_xbf = 0;                 // also rq later (same size)
  size_t o_wqkv = o_xbf + SZ;       // 3 stacked weight matrices
  size_t o_wo = o_wqkv + 3 * WSZ;
  size_t o_g2 = o_wo + WSZ;
  size_t o_qkv = o_g2 + WSZ;        // later: xloc f32 [0, 2*SZ) and ybf [2*SZ, 3*SZ)
  size_t o_rk = o_qkv + QKVSZ;
  size_t o_vt = o_rk + SZ;
  size_t o_z = o_vt + SZ;
  size_t o_bqkv = o_z + (size_t)S * 12 * 4;
  size_t need = o_bqkv + 4608 * 4;
  if (ws_size < need) return;  // insufficient scratch -> fail loudly

  unsigned short* xbf = (unsigned short*)(ws + o_xbf);
  unsigned short* wqkv = (unsigned short*)(ws + o_wqkv);
  unsigned short* wob = (unsigned short*)(ws + o_wo);
  unsigned short* g2b = (unsigned short*)(ws + o_g2);
  unsigned short* qkv = (unsigned short*)(ws + o_qkv);
  unsigned short* rkb = (unsigned short*)(ws + o_rk);
  unsigned short* vtb = (unsigned short*)(ws + o_vt);
  float* zbuf = (float*)(ws + o_z);
  float* bqkv = (float*)(ws + o_bqkv);
  unsigned short* rqb = xbf;                                // aliases xbf (dead after QKV gemm)
  float* xloc = (float*)(ws + o_qkv);                       // aliases qkv (dead after rope/vtrans)
  unsigned short* ybf = (unsigned short*)(ws + o_qkv + 2 * SZ);  // after xloc region

  // 1) casts
  {
    int n4 = (S * 1536) / 4;
    cast_f32_bf16_x4<<<(n4 + 255) / 256, 256, 0, stream>>>(x, xbf, n4);
    int w4 = (1536 * 1536) / 4;
    int wg = (w4 + 255) / 256;
    cast_f32_bf16_x4<<<wg, 256, 0, stream>>>(Wq, wqkv, w4);
    cast_f32_bf16_x4<<<wg, 256, 0, stream>>>(Wk, wqkv + (size_t)1536 * 1536, w4);
    cast_f32_bf16_x4<<<wg, 256, 0, stream>>>(Wv, wqkv + (size_t)2 * 1536 * 1536, w4);
    cast_f32_bf16_x4<<<wg, 256, 0, stream>>>(Wo, wob, w4);
  }
  // bias concat for merged QKV
  hipMemcpyAsync(bqkv, bq, 1536 * 4, hipMemcpyDeviceToDevice, stream);
  hipMemcpyAsync(bqkv + 1536, bk, 1536 * 4, hipMemcpyDeviceToDevice, stream);
  hipMemcpyAsync(bqkv + 3072, bv, 1536 * 4, hipMemcpyDeviceToDevice, stream);

  // 2) block-diagonal G2 = g_kv @ Wlin^T
  hipMemsetAsync(g2b, 0, WSZ, stream);
  g2fill_kernel<<<dim3(12, 128), 128, 0, stream>>>(g_kv, Wlin, g2b);

  // 3) merged QKV projection: qkv[S][4608]
  {
    dim3 ggrid((S + 127) / 128, 36);
    gemm_bt<0><<<ggrid, 256, 0, stream>>>(xbf, wqkv, bqkv, qkv, S, 4608, 1536, nullptr, nullptr);
  }

  // 4) RMS + RoPE (+z for q); reads qkv with row stride 4608
  rms_rope_kernel<<<S, 256, 0, stream>>>(qkv, freqs, gq, g_kmean, rqb, zbuf, S, 4608, hgp, wgp);
  rms_rope_kernel<<<S, 256, 0, stream>>>(qkv + 1536, freqs, gk, nullptr, rkb, nullptr, S, 4608, hgp, wgp);

  // 5) V transpose (from qkv v-block, stride 4608)
  vtrans_kernel<<<dim3((S + 63) / 64, 24), 256, 0, stream>>>(qkv + 3072, vtb, S, 4608);

  // 6) attention -> xloc (f32) [overwrites qkv region; q/k/v parts are dead]
  attn_kernel<<<dim3((S + 127) / 128, 12), 256, 0, stream>>>(rqb, rkb, vtb, xloc, S);

  // 7) xg = (rq @ G2) * z + xloc + blin  -> ybf
  {
    dim3 ggrid((S + 127) / 128, 12);
    gemm_bt<2><<<ggrid, 256, 0, stream>>>(rqb, g2b, blin, ybf, S, 1536, 1536, xloc, zbuf);
    // 8) out = ybf @ Wo^T + bo -> f32 d_out
    gemm_bt<1><<<ggrid, 256, 0, stream>>>(ybf, wob, bo, (float*)d_out, S, 1536, 1536, nullptr, nullptr);
  }
}

// Round 3
// 480.237 us; speedup vs baseline: 1.4485x; 1.4433x over previous
//
#include <hip/hip_runtime.h>

typedef short s16x8 __attribute__((ext_vector_type(8)));
typedef float f32x4 __attribute__((ext_vector_type(4)));
typedef unsigned short u16x4 __attribute__((ext_vector_type(4)));

#define QSCALE (0.08838834764831845f * 1.4426950408889634f)

__device__ __forceinline__ unsigned short f2bf(float f) {
  unsigned int u = __float_as_uint(f);
  u += 0x7fffu + ((u >> 16) & 1u);
  return (unsigned short)(u >> 16);
}
__device__ __forceinline__ float bf2f(unsigned short h) {
  return __uint_as_float((unsigned int)h << 16);
}
__device__ __forceinline__ float fast_exp2(float x) {
  float r;
  asm("v_exp_f32 %0, %1" : "=v"(r) : "v"(x));
  return r;
}

__device__ __forceinline__ void gload16(const void* gp, void* lp) {
  __builtin_amdgcn_global_load_lds(
      (const __attribute__((address_space(1))) void*)gp,
      (__attribute__((address_space(3))) void*)lp,
      16, 0, 0);
}

// ---------------- cast f32 -> bf16, 4 at a time ----------------
__global__ void cast_f32_bf16_x4(const float* __restrict__ in,
                                 unsigned short* __restrict__ out, int n4) {
  int i = blockIdx.x * 256 + threadIdx.x;
  if (i >= n4) return;
  f32x4 v = *((const f32x4*)in + i);
  u16x4 o;
  o[0] = f2bf(v[0]); o[1] = f2bf(v[1]); o[2] = f2bf(v[2]); o[3] = f2bf(v[3]);
  *((u16x4*)out + i) = o;
}

// ---------------- G2[h][m][d] = (1/QSCALE) * sum_j g_kv[h][d][j] * Wlin[m][j], block-diag ----
// (compensates the QSCALE folded into rq)
__global__ void g2fill_kernel(const float* __restrict__ g_kv,
                              const float* __restrict__ Wlin,
                              unsigned short* __restrict__ G2) {
  int h = blockIdx.x, m = blockIdx.y, d = threadIdx.x;
  const float* gk = g_kv + ((size_t)h * 128 + d) * 128;
  const float* wl = Wlin + (size_t)m * 128;
  float s = 0.f;
  for (int j = 0; j < 128; ++j) s += gk[j] * wl[j];
  G2[((size_t)h * 128 + m) * 1536 + h * 128 + d] = f2bf(s * (1.0f / QSCALE));
}

// ---------------- GEMM: C[M,N] = A[M,K] @ B[N,K]^T (+ epilogue) ----------------
// MODE 0: bf16 out, +bias[cc]
// MODE 1: f32 out, +bias[cc]
// MODE 2: bf16 out, v*z[rr,cc>>7] + xloc[rr,cc] + bias[cc&127]
template <int MODE>
__global__ __launch_bounds__(256) void gemm_bt(
    const unsigned short* __restrict__ A, const unsigned short* __restrict__ B,
    const float* __restrict__ bias, void* __restrict__ Cout,
    int M, int N, int K,
    const float* __restrict__ xloc, const float* __restrict__ zbuf) {
  __shared__ __align__(16) unsigned short Asm_[128 * 64];
  __shared__ __align__(16) unsigned short Bsm_[128 * 64];
  const int tid = threadIdx.x;
  const int wid = tid >> 6, lane = tid & 63;
  const int mt = blockIdx.x, nt = blockIdx.y;
  const int wr = wid >> 1, wc = wid & 1;
  f32x4 acc[4][4] = {};

  const int st_srccol = ((((lane & 7) << 4) ^ ((lane >> 3) << 4)) >> 1);  // elements
  const int st_rowoff = (lane >> 3);

  for (int k0 = 0; k0 < K; k0 += 64) {
    __syncthreads();
#pragma unroll
    for (int r = 0; r < 4; ++r) {
      int c = wid * 4 + r;
      int lrow = c * 8 + st_rowoff;
      int arow = mt * 128 + lrow; if (arow > M - 1) arow = M - 1;
      gload16(A + (size_t)arow * K + k0 + st_srccol,
              (char*)Asm_ + c * 1024 + lane * 16);
      int brow = nt * 128 + lrow;
      gload16(B + (size_t)brow * K + k0 + st_srccol,
              (char*)Bsm_ + c * 1024 + lane * 16);
    }
    __syncthreads();
#pragma unroll
    for (int kk = 0; kk < 2; ++kk) {
      int cb = (kk * 64 + ((lane >> 4) << 4)) ^ ((lane & 7) << 4);
      s16x8 af[4], bfr[4];
#pragma unroll
      for (int m = 0; m < 4; ++m)
        af[m] = *(const s16x8*)((const char*)Asm_ + (wr * 64 + m * 16 + (lane & 15)) * 128 + cb);
#pragma unroll
      for (int n = 0; n < 4; ++n)
        bfr[n] = *(const s16x8*)((const char*)Bsm_ + (wc * 64 + n * 16 + (lane & 15)) * 128 + cb);
#pragma unroll
      for (int m = 0; m < 4; ++m)
#pragma unroll
        for (int n = 0; n < 4; ++n)
          acc[m][n] = __builtin_amdgcn_mfma_f32_16x16x32_bf16(af[m], bfr[n], acc[m][n], 0, 0, 0);
    }
  }
  const int rb = mt * 128 + wr * 64, cbse = nt * 128 + wc * 64;
#pragma unroll
  for (int m = 0; m < 4; ++m) {
#pragma unroll
    for (int n = 0; n < 4; ++n) {
#pragma unroll
      for (int rg = 0; rg < 4; ++rg) {
        int rr = rb + m * 16 + ((lane >> 4) << 2) + rg;
        int cc = cbse + n * 16 + (lane & 15);
        if (rr < M) {
          float v = acc[m][n][rg];
          if (MODE == 0) {
            v += bias[cc];
            ((unsigned short*)Cout)[(size_t)rr * N + cc] = f2bf(v);
          } else if (MODE == 1) {
            v += bias[cc];
            ((float*)Cout)[(size_t)rr * N + cc] = v;
          } else {
            v = v * zbuf[(size_t)rr * 12 + (cc >> 7)] + xloc[(size_t)rr * N + cc] + bias[cc & 127];
            ((unsigned short*)Cout)[(size_t)rr * N + cc] = f2bf(v);
          }
        }
      }
    }
  }
}

// ---------------- RMS + RoPE (+ z for the q path); input row stride ld ----------------
// oscale is folded into the rotated output (QSCALE for q, 1.0 for k).
__global__ __launch_bounds__(256) void rms_rope_kernel(
    const unsigned short* __restrict__ pre, const float* __restrict__ freqs,
    const float* __restrict__ g, const float* __restrict__ g_kmean,
    unsigned short* __restrict__ outr, float* __restrict__ zout,
    int S, int ld, float oscale,
    const int* __restrict__ hgp, const int* __restrict__ wgp) {
  const int s = blockIdx.x;
  const int tid = threadIdx.x;
  const int lane = tid & 63, wid = tid >> 6;
  const unsigned short* row = pre + (size_t)s * ld;
  unsigned int pv0, pv1, pv2;
  float ssq = 0.f;
  {
    pv0 = *(const unsigned int*)(row + 2 * (tid));
    pv1 = *(const unsigned int*)(row + 2 * (tid + 256));
    pv2 = *(const unsigned int*)(row + 2 * (tid + 512));
    float a0 = bf2f((unsigned short)(pv0 & 0xffffu)), b0 = bf2f((unsigned short)(pv0 >> 16));
    float a1 = bf2f((unsigned short)(pv1 & 0xffffu)), b1 = bf2f((unsigned short)(pv1 >> 16));
    float a2 = bf2f((unsigned short)(pv2 & 0xffffu)), b2 = bf2f((unsigned short)(pv2 >> 16));
    ssq = a0 * a0 + b0 * b0 + a1 * a1 + b1 * b1 + a2 * a2 + b2 * b2;
  }
#pragma unroll
  for (int m = 1; m < 64; m <<= 1) ssq += __shfl_xor(ssq, m, 64);
  __shared__ float wpart[4];
  if (lane == 0) wpart[wid] = ssq;
  __syncthreads();
  float tot = wpart[0] + wpart[1] + wpart[2] + wpart[3];
  float rms = rsqrtf(tot * (1.0f / 1536.0f) + 1e-6f);
  const int Wg = *wgp;
  const int HWg = (*hgp) * Wg;
  int fi = s / HWg; int rem = s - fi * HWg;
  int hi = rem / Wg; int wi = rem - hi * Wg;
  unsigned int pvs[3] = {pv0, pv1, pv2};
#pragma unroll
  for (int rd = 0; rd < 3; ++rd) {
    int p = tid + rd * 256;
    int c = p & 63;
    int fidx = (c < 22) ? fi : ((c < 43) ? hi : wi);
    float cr = freqs[fidx * 128 + 2 * c];
    float ci = freqs[fidx * 128 + 2 * c + 1];
    float xr = bf2f((unsigned short)(pvs[rd] & 0xffffu)) * rms * g[2 * p];
    float xi = bf2f((unsigned short)(pvs[rd] >> 16)) * rms * g[2 * p + 1];
    float yr = (xr * cr - xi * ci) * oscale;
    float yi = (xr * ci + xi * cr) * oscale;
    unsigned int ow = (unsigned int)f2bf(yr) | ((unsigned int)f2bf(yi) << 16);
    *(unsigned int*)(outr + (size_t)s * 1536 + 2 * p) = ow;
    if (zout != nullptr) {
      int head = p >> 6;
      float part = fmaxf(xr, 0.f) * g_kmean[head * 128 + 2 * c] +
                   fmaxf(xi, 0.f) * g_kmean[head * 128 + 2 * c + 1];
#pragma unroll
      for (int m = 1; m < 64; m <<= 1) part += __shfl_xor(part, m, 64);
      if (lane == 0) zout[(size_t)s * 12 + head] = 1.0f / (part + 1e-6f);
    }
  }
}

// ---------------- V transpose: vpre (S, ld cols used 64) bf16 -> vt (1536, S) bf16 ----------------
__global__ __launch_bounds__(256) void vtrans_kernel(const unsigned short* __restrict__ vpre,
                                                     unsigned short* __restrict__ vt, int S, int ld) {
  __shared__ unsigned short tile[64][66];
  int t0 = blockIdx.x * 64, c0 = blockIdx.y * 64;
  int tid = threadIdx.x;
#pragma unroll
  for (int rep = 0; rep < 16; ++rep) {
    int lin = rep * 256 + tid;
    int i = lin >> 6, j = lin & 63;
    int t = t0 + i; if (t > S - 1) t = S - 1;
    tile[i][j] = vpre[(size_t)t * ld + c0 + j];
  }
  __syncthreads();
#pragma unroll
  for (int rep = 0; rep < 16; ++rep) {
    int lin = rep * 256 + tid;
    int j = lin >> 6, i = lin & 63;
    int t = t0 + i;
    if (t < S) vt[(size_t)(c0 + j) * S + t] = tile[i][j];
  }
}

// ---------------- Flash attention, no-max softmax (q,k RMS-normed => exp can't overflow) ----
__global__ __launch_bounds__(256) void attn_kernel(
    const unsigned short* __restrict__ rq, const unsigned short* __restrict__ rk,
    const unsigned short* __restrict__ vt, float* __restrict__ xloc, int S) {
  __shared__ __align__(16) unsigned short Ks[2][64 * 128];  // [tok][d] swizzled
  __shared__ __align__(16) unsigned short Vs[2][64 * 128];  // [d][tok] swizzled (from vt)
  __shared__ __align__(16) unsigned short Ps[4][32 * 64];   // per-wave [q][tok] swizzled
  const int tid = threadIdx.x, wid = tid >> 6, lane = tid & 63;
  const int g = lane >> 4, c = lane & 15;
  const int h = blockIdx.y;
  const int q0 = blockIdx.x * 128 + wid * 32;

  // Q B-fragments: qf[qh][kk] = Q[q = q0+qh*16+c][dim = kk*32 + g*8 + j]  (pre-scaled by QSCALE)
  s16x8 qf[2][4];
#pragma unroll
  for (int qh = 0; qh < 2; ++qh) {
    int qrow = q0 + qh * 16 + c; if (qrow > S - 1) qrow = S - 1;
    const unsigned short* qp = rq + (size_t)qrow * 1536 + h * 128 + g * 8;
#pragma unroll
    for (int kk = 0; kk < 4; ++kk) qf[qh][kk] = *(const s16x8*)(qp + kk * 32);
  }
  f32x4 o[2][8] = {};
  float lsum[2] = {0.f, 0.f};  // per-lane partial row-sums (reduced at the end)
  unsigned short* psw = Ps[wid];

  {  // prologue: stage tile 0
#pragma unroll
    for (int r = 0; r < 4; ++r) {
      int ch = wid * 4 + r;
      int lrow = ch * 4 + (lane >> 4);
      int cb = ((lane & 15) << 4) ^ ((lrow & 7) << 4);
      int trow = lrow; if (trow > S - 1) trow = S - 1;
      gload16(rk + (size_t)trow * 1536 + h * 128 + (cb >> 1),
              (char*)Ks[0] + ch * 1024 + lane * 16);
      int drow = ch * 8 + (lane >> 3);
      int cb2 = ((lane & 7) << 4) ^ ((drow & 7) << 4);
      int tok = (cb2 >> 1); if (tok + 8 > S) tok = S - 8;
      gload16(vt + (size_t)(h * 128 + drow) * S + tok,
              (char*)Vs[0] + ch * 1024 + lane * 16);
    }
  }
  __syncthreads();
  int cur = 0;
  for (int t0 = 0; t0 < S; t0 += 64) {
    // issue next tile's staging first (hides under compute; barrier at loop end drains)
    if (t0 + 64 < S) {
      int nt0 = t0 + 64;
#pragma unroll
      for (int r = 0; r < 4; ++r) {
        int ch = wid * 4 + r;
        int lrow = ch * 4 + (lane >> 4);
        int cb = ((lane & 15) << 4) ^ ((lrow & 7) << 4);
        int trow = nt0 + lrow; if (trow > S - 1) trow = S - 1;
        gload16(rk + (size_t)trow * 1536 + h * 128 + (cb >> 1),
                (char*)Ks[cur ^ 1] + ch * 1024 + lane * 16);
        int drow = ch * 8 + (lane >> 3);
        int cb2 = ((lane & 7) << 4) ^ ((drow & 7) << 4);
        int tok = nt0 + (cb2 >> 1); if (tok + 8 > S) tok = S - 8;
        gload16(vt + (size_t)(h * 128 + drow) * S + tok,
                (char*)Vs[cur ^ 1] + ch * 1024 + lane * 16);
      }
    }
    // ---- QK^T (swapped): sc[qh][ct][rg] = log2e*scale * S[token=ct*16+4g+rg][q=qh*16+c]
    f32x4 sc[2][4] = {};
    __builtin_amdgcn_s_setprio(1);
#pragma unroll
    for (int ct = 0; ct < 4; ++ct) {
#pragma unroll
      for (int kk = 0; kk < 4; ++kk) {
        s16x8 kfr = *(const s16x8*)((const char*)Ks[cur] + (ct * 16 + c) * 256 +
                                    ((kk * 64 + (g << 4)) ^ ((c & 7) << 4)));
        sc[0][ct] = __builtin_amdgcn_mfma_f32_16x16x32_bf16(kfr, qf[0][kk], sc[0][ct], 0, 0, 0);
        sc[1][ct] = __builtin_amdgcn_mfma_f32_16x16x32_bf16(kfr, qf[1][kk], sc[1][ct], 0, 0, 0);
      }
    }
    __builtin_amdgcn_s_setprio(0);
    // ---- softmax numerator: p = exp2(sc), truncated to bf16; l accumulates truncated p
    const bool full = (t0 + 64 <= S);
#pragma unroll
    for (int qh = 0; qh < 2; ++qh) {
      float rs0 = 0.f, rs1 = 0.f, rs2 = 0.f, rs3 = 0.f;
      char* prow = (char*)psw + (qh * 16 + c) * 128;
#pragma unroll
      for (int ct = 0; ct < 4; ++ct) {
#pragma unroll
        for (int hh = 0; hh < 2; ++hh) {
          float p0, p1;
          if (full) {
            p0 = fast_exp2(sc[qh][ct][2 * hh]);
            p1 = fast_exp2(sc[qh][ct][2 * hh + 1]);
          } else {
            int T = t0 + ct * 16 + 4 * g + 2 * hh;
            p0 = (T < S) ? fast_exp2(sc[qh][ct][2 * hh]) : 0.f;
            p1 = (T + 1 < S) ? fast_exp2(sc[qh][ct][2 * hh + 1]) : 0.f;
          }
          unsigned int u0 = __float_as_uint(p0) & 0xffff0000u;
          unsigned int u1 = __float_as_uint(p1) & 0xffff0000u;
          if (hh == 0) { rs0 += __uint_as_float(u0); rs1 += __uint_as_float(u1); }
          else         { rs2 += __uint_as_float(u0); rs3 += __uint_as_float(u1); }
          unsigned int w = (u0 >> 16) | u1;
          *(unsigned int*)(prow + ((ct * 32 + 8 * g + 4 * hh) ^ ((c & 7) << 4))) = w;
        }
      }
      lsum[qh] += (rs0 + rs1) + (rs2 + rs3);
    }
    // ---- PV: o[qh] += P[q][tok] @ Vt[d][tok]
    __builtin_amdgcn_s_setprio(1);
#pragma unroll
    for (int kt = 0; kt < 2; ++kt) {
      const int pb = (kt * 64 + (g << 4)) ^ ((c & 7) << 4);
      s16x8 pa0 = *(const s16x8*)((const char*)psw + c * 128 + pb);
      s16x8 pa1 = *(const s16x8*)((const char*)psw + (16 + c) * 128 + pb);
#pragma unroll
      for (int nf = 0; nf < 8; ++nf) {
        s16x8 vfr = *(const s16x8*)((const char*)Vs[cur] + (nf * 16 + c) * 128 + pb);
        o[0][nf] = __builtin_amdgcn_mfma_f32_16x16x32_bf16(pa0, vfr, o[0][nf], 0, 0, 0);
        o[1][nf] = __builtin_amdgcn_mfma_f32_16x16x32_bf16(pa1, vfr, o[1][nf], 0, 0, 0);
      }
    }
    __builtin_amdgcn_s_setprio(0);
    __syncthreads();
    cur ^= 1;
  }
  // epilogue: rows q = q0+qh*16+4g+rg, cols d = nf*16+c
#pragma unroll
  for (int qh = 0; qh < 2; ++qh) {
    float l = lsum[qh];
    l += __shfl_xor(l, 16, 64);
    l += __shfl_xor(l, 32, 64);
    float invl = 1.0f / l;  // lane (any g, c) holds inv-sum for q-row qh*16+c
    f32x4 iv;
#pragma unroll
    for (int rg = 0; rg < 4; ++rg) iv[rg] = __shfl(invl, (g << 2) + rg, 64);
#pragma unroll
    for (int nf = 0; nf < 8; ++nf) {
#pragma unroll
      for (int rg = 0; rg < 4; ++rg) {
        int qrow = q0 + qh * 16 + 4 * g + rg;
        if (qrow < S)
          xloc[(size_t)qrow * 1536 + h * 128 + nf * 16 + c] = o[qh][nf][rg] * iv[rg];
      }
    }
  }
}

extern "C" void kernel_launch(void* const* d_in, const int* in_sizes, int n_in,
                              void* d_out, int out_size, void* d_ws, size_t ws_size,
                              hipStream_t stream) {
  const float* x = (const float*)d_in[0];
  const float* freqs = (const float*)d_in[1];
  const float* g_kmean = (const float*)d_in[2];
  const float* g_kv = (const float*)d_in[3];
  const float* Wq = (const float*)d_in[4];  const float* bq = (const float*)d_in[5];
  const float* Wk = (const float*)d_in[6];  const float* bk = (const float*)d_in[7];
  const float* Wv = (const float*)d_in[8];  const float* bv = (const float*)d_in[9];
  const float* Wo = (const float*)d_in[10]; const float* bo = (const float*)d_in[11];
  const float* gq = (const float*)d_in[12]; const float* gk = (const float*)d_in[13];
  const float* Wlin = (const float*)d_in[14]; const float* blin = (const float*)d_in[15];
  const int* hgp = (const int*)d_in[17];
  const int* wgp = (const int*)d_in[18];

  const int S = in_sizes[0] / 1536;

  char* ws = (char*)d_ws;
  const size_t SZ = (size_t)S * 1536 * 2;        // bf16 (S,1536)
  const size_t WSZ = (size_t)1536 * 1536 * 2;    // bf16 1536^2
  const size_t QKVSZ = (size_t)S * 4608 * 2;     // bf16 (S,4608)
  size_t o_xbf = 0;                 // also rq later (same size)
  size_t o_wqkv = o_xbf + SZ;       // 3 stacked weight matrices
  size_t o_wo = o_wqkv + 3 * WSZ;
  size_t o_g2 = o_wo + WSZ;
  size_t o_qkv = o_g2 + WSZ;        // later: xloc f32 [0, 2*SZ) and ybf [2*SZ, 3*SZ)
  size_t o_rk = o_qkv + QKVSZ;
  size_t o_vt = o_rk + SZ;
  size_t o_z = o_vt + SZ;
  size_t o_bqkv = o_z + (size_t)S * 12 * 4;
  size_t need = o_bqkv + 4608 * 4;
  if (ws_size < need) return;  // insufficient scratch -> fail loudly

  unsigned short* xbf = (unsigned short*)(ws + o_xbf);
  unsigned short* wqkv = (unsigned short*)(ws + o_wqkv);
  unsigned short* wob = (unsigned short*)(ws + o_wo);
  unsigned short* g2b = (unsigned short*)(ws + o_g2);
  unsigned short* qkv = (unsigned short*)(ws + o_qkv);
  unsigned short* rkb = (unsigned short*)(ws + o_rk);
  unsigned short* vtb = (unsigned short*)(ws + o_vt);
  float* zbuf = (float*)(ws + o_z);
  float* bqkv = (float*)(ws + o_bqkv);
  unsigned short* rqb = xbf;                                // aliases xbf (dead after QKV gemm)
  float* xloc = (float*)(ws + o_qkv);                       // aliases qkv (dead after rope/vtrans)
  unsigned short* ybf = (unsigned short*)(ws + o_qkv + 2 * SZ);  // after xloc region

  // 1) casts
  {
    int n4 = (S * 1536) / 4;
    cast_f32_bf16_x4<<<(n4 + 255) / 256, 256, 0, stream>>>(x, xbf, n4);
    int w4 = (1536 * 1536) / 4;
    int wg = (w4 + 255) / 256;
    cast_f32_bf16_x4<<<wg, 256, 0, stream>>>(Wq, wqkv, w4);
    cast_f32_bf16_x4<<<wg, 256, 0, stream>>>(Wk, wqkv + (size_t)1536 * 1536, w4);
    cast_f32_bf16_x4<<<wg, 256, 0, stream>>>(Wv, wqkv + (size_t)2 * 1536 * 1536, w4);
    cast_f32_bf16_x4<<<wg, 256, 0, stream>>>(Wo, wob, w4);
  }
  // bias concat for merged QKV
  hipMemcpyAsync(bqkv, bq, 1536 * 4, hipMemcpyDeviceToDevice, stream);
  hipMemcpyAsync(bqkv + 1536, bk, 1536 * 4, hipMemcpyDeviceToDevice, stream);
  hipMemcpyAsync(bqkv + 3072, bv, 1536 * 4, hipMemcpyDeviceToDevice, stream);

  // 2) block-diagonal G2 = g_kv @ Wlin^T (pre-scaled by 1/QSCALE)
  hipMemsetAsync(g2b, 0, WSZ, stream);
  g2fill_kernel<<<dim3(12, 128), 128, 0, stream>>>(g_kv, Wlin, g2b);

  // 3) merged QKV projection: qkv[S][4608]
  {
    dim3 ggrid((S + 127) / 128, 36);
    gemm_bt<0><<<ggrid, 256, 0, stream>>>(xbf, wqkv, bqkv, qkv, S, 4608, 1536, nullptr, nullptr);
  }

  // 4) RMS + RoPE (+z for q); reads qkv with row stride 4608; q scaled by QSCALE
  rms_rope_kernel<<<S, 256, 0, stream>>>(qkv, freqs, gq, g_kmean, rqb, zbuf, S, 4608, QSCALE, hgp, wgp);
  rms_rope_kernel<<<S, 256, 0, stream>>>(qkv + 1536, freqs, gk, nullptr, rkb, nullptr, S, 4608, 1.0f, hgp, wgp);

  // 5) V transpose (from qkv v-block, stride 4608)
  vtrans_kernel<<<dim3((S + 63) / 64, 24), 256, 0, stream>>>(qkv + 3072, vtb, S, 4608);

  // 6) attention -> xloc (f32) [overwrites qkv region; q/k/v parts are dead]
  attn_kernel<<<dim3((S + 127) / 128, 12), 256, 0, stream>>>(rqb, rkb, vtb, xloc, S);

  // 7) xg = (rq @ G2) * z + xloc + blin  -> ybf   (G2 pre-scaled compensates rq's QSCALE)
  {
    dim3 ggrid((S + 127) / 128, 12);
    gemm_bt<2><<<ggrid, 256, 0, stream>>>(rqb, g2b, blin, ybf, S, 1536, 1536, xloc, zbuf);
    // 8) out = ybf @ Wo^T + bo -> f32 d_out
    gemm_bt<1><<<ggrid, 256, 0, stream>>>(ybf, wob, bo, (float*)d_out, S, 1536, 1536, nullptr, nullptr);
  }
}